// Round 16
// baseline (93.287 us; speedup 1.0000x reference)
//
#include <hip/hip_runtime.h>

#define TOTAL     4194304
#define DIM       32
#define NTOK      (TOTAL / DIM)   // 131072 tokens
#define NCODE     1024
#define DELTA_EPS 2e-3f
#define FLAGBIT   0x40000000

typedef _Float16 half8   __attribute__((ext_vector_type(8)));
typedef float    floatx4 __attribute__((ext_vector_type(4)));

// ---------------- prep: codebook -> f16 hi/lo split in FRAGMENT ORDER + (-0.5*|e|^2) ----
// Fragment slot for code k: gs = k>>4 (global step 0..63), l15 = k&15;
// slot = gs*64 + l4*16 + l15 (8 halves = 16 B per slot).
__global__ __launch_bounds__(64) void vq_prep(
    const float* __restrict__ cb, float* __restrict__ nhb,
    _Float16* __restrict__ Eh, _Float16* __restrict__ El)
{
    const int k = blockIdx.x * 64 + threadIdx.x;   // code id
    const float4* e4 = reinterpret_cast<const float4*>(cb) + (size_t)k * 8;
    float v[DIM];
    float4 t[8];
#pragma unroll
    for (int j = 0; j < 8; ++j) t[j] = e4[j];
#pragma unroll
    for (int j = 0; j < 8; ++j) {
        v[4 * j + 0] = t[j].x; v[4 * j + 1] = t[j].y;
        v[4 * j + 2] = t[j].z; v[4 * j + 3] = t[j].w;
    }
    float e2 = 0.0f;
#pragma unroll
    for (int i = 0; i < DIM; ++i) e2 = fmaf(v[i], v[i], e2);   // sequential: matches rescore
    nhb[k] = -0.5f * e2;

    const int gs = k >> 4, l15 = k & 15;
#pragma unroll
    for (int l4 = 0; l4 < 4; ++l4) {
        half8 h, lo;
#pragma unroll
        for (int j = 0; j < 8; ++j) {
            float x = v[l4 * 8 + j];
            _Float16 hh = (_Float16)x;
            h[j]  = hh;
            lo[j] = (_Float16)(x - (float)hh);
        }
        const int slot = gs * 64 + l4 * 16 + l15;
        *reinterpret_cast<half8*>(Eh + (size_t)slot * 8) = h;
        *reinterpret_cast<half8*>(El + (size_t)slot * 8) = lo;
    }
}

// ---------------- main: split-K MFMA argmax (B in registers) + merge + fused rescore ---
// 256 blocks x 1024 thr (16 waves). Wave w owns codes [w*64, w*64+64) -- B fragments
// live in VGPRs for the whole kernel. Block's 512 token x-fragments staged in LDS once.
// Sweep: 32 tiles x {2 ds_read + 12 MFMA + epilogue}; then [16x512] LDS merge + rescore.
__global__ __launch_bounds__(1024) void vq_main(
    const float* __restrict__ w, const float* __restrict__ c,
    const float* __restrict__ nhb, const _Float16* __restrict__ Eh,
    const _Float16* __restrict__ El, const float* __restrict__ cb,
    int* __restrict__ out)
{
    __shared__ _Float16 sXh[2048 * 8];   // 32 KB: [tile(32)][lane(64)][8 halves]
    __shared__ _Float16 sXl[2048 * 8];   // 32 KB
    __shared__ float2   sPart[16 * 512]; // 64 KB: [partial(16)][token(512)]
    __shared__ int      sOut[512];       // 2 KB

    const int tid  = threadIdx.x;
    const int lane = tid & 63;
    const int wid  = tid >> 6;              // 0..15
    const int tok0 = blockIdx.x * 512;
    const int l15  = lane & 15;
    const int l4   = lane >> 4;

    // ---- B fragments for this wave's 64 codes (4 steps), into registers
    half8 beh[4], bel[4];
    float bnh[4];
    unsigned bix[4];
#pragma unroll
    for (int s = 0; s < 4; ++s) {
        const int gs = wid * 4 + s;
        beh[s] = *reinterpret_cast<const half8*>(Eh + (size_t)(gs * 64 + lane) * 8);
        bel[s] = *reinterpret_cast<const half8*>(El + (size_t)(gs * 64 + lane) * 8);
        bnh[s] = nhb[gs * 16 + l15];
        bix[s] = 1023u - (unsigned)(gs * 16 + l15);
    }

    // ---- stage x fragments: 2 threads per token (each covers 16 dims / 2 quarters)
    {
        const int t    = tid >> 1;          // token 0..511
        const int half = tid & 1;           // dims [half*16, half*16+16)
        const int token = tok0 + t;
        const float4* pw = reinterpret_cast<const float4*>(w + (size_t)token * DIM + half * 16);
        const float4* pc = reinterpret_cast<const float4*>(c + (size_t)token * DIM + half * 16);
        float4 a0 = pw[0], a1 = pw[1], a2 = pw[2], a3 = pw[3];
        float4 b0 = pc[0], b1 = pc[1], b2 = pc[2], b3 = pc[3];
        float xs[16] = {a0.x - b0.x, a0.y - b0.y, a0.z - b0.z, a0.w - b0.w,
                        a1.x - b1.x, a1.y - b1.y, a1.z - b1.z, a1.w - b1.w,
                        a2.x - b2.x, a2.y - b2.y, a2.z - b2.z, a2.w - b2.w,
                        a3.x - b3.x, a3.y - b3.y, a3.z - b3.z, a3.w - b3.w};
        const int tile = t >> 4, row = t & 15;
#pragma unroll
        for (int qq = 0; qq < 2; ++qq) {
            half8 h, lo;
#pragma unroll
            for (int j = 0; j < 8; ++j) {
                float x = xs[qq * 8 + j];
                _Float16 hh = (_Float16)x;
                h[j]  = hh;
                lo[j] = (_Float16)(x - (float)hh);
            }
            const int q = half * 2 + qq;                 // k-quarter 0..3
            const int slot = tile * 64 + q * 16 + row;
            *reinterpret_cast<half8*>(sXh + (size_t)slot * 8) = h;
            *reinterpret_cast<half8*>(sXl + (size_t)slot * 8) = lo;
        }
    }
    __syncthreads();   // x fragments visible

    const float NEGINF = __uint_as_float(0xFF800000u);

    // ---- sweep 32 tiles; stagger start per wave to spread LDS traffic
#pragma unroll 4
    for (int tt = 0; tt < 32; ++tt) {
        const int tile = (tt + wid * 2) & 31;
        const half8 xh = *reinterpret_cast<const half8*>(sXh + (size_t)(tile * 64 + lane) * 8);
        const half8 xl = *reinterpret_cast<const half8*>(sXl + (size_t)(tile * 64 + lane) * 8);

        float bb[4], ss[4];
#pragma unroll
        for (int r = 0; r < 4; ++r) { bb[r] = NEGINF; ss[r] = NEGINF; }

#pragma unroll
        for (int sp = 0; sp < 2; ++sp) {
            const int s0 = 2 * sp, s1 = 2 * sp + 1;
            const floatx4 n0 = {bnh[s0], bnh[s0], bnh[s0], bnh[s0]};
            const floatx4 n1 = {bnh[s1], bnh[s1], bnh[s1], bnh[s1]};
            floatx4 aA = __builtin_amdgcn_mfma_f32_16x16x32_f16(xh, beh[s0], n0, 0, 0, 0);
            aA = __builtin_amdgcn_mfma_f32_16x16x32_f16(xl, beh[s0], aA, 0, 0, 0);
            aA = __builtin_amdgcn_mfma_f32_16x16x32_f16(xh, bel[s0], aA, 0, 0, 0);
            floatx4 aB = __builtin_amdgcn_mfma_f32_16x16x32_f16(xh, beh[s1], n1, 0, 0, 0);
            aB = __builtin_amdgcn_mfma_f32_16x16x32_f16(xl, beh[s1], aB, 0, 0, 0);
            aB = __builtin_amdgcn_mfma_f32_16x16x32_f16(xh, bel[s1], aB, 0, 0, 0);
#pragma unroll
            for (int r = 0; r < 4; ++r) {
                float pA = __uint_as_float((__float_as_uint(aA[r]) & 0xFFFFFC00u) | bix[s0]);
                float pB = __uint_as_float((__float_as_uint(aB[r]) & 0xFFFFFC00u) | bix[s1]);
                ss[r] = fmaxf(ss[r], __builtin_amdgcn_fmed3f(pA, pB, bb[r]));
                bb[r] = fmaxf(fmaxf(bb[r], pA), pB);
            }
        }

        // reduce over the 16 code-lanes of this partial
#pragma unroll
        for (int sh = 1; sh < 16; sh <<= 1) {
#pragma unroll
            for (int r = 0; r < 4; ++r) {
                float bB = __shfl_xor(bb[r], sh);
                float sB = __shfl_xor(ss[r], sh);
                ss[r] = fmaxf(fmaxf(ss[r], sB), fminf(bb[r], bB));
                bb[r] = fmaxf(bb[r], bB);
            }
        }
        if (l15 == 0) {
#pragma unroll
            for (int r = 0; r < 4; ++r) {
                const int trow = tile * 16 + l4 * 4 + r;   // token within block
                sPart[wid * 512 + trow] = make_float2(bb[r], ss[r]);
            }
        }
    }
    __syncthreads();   // all partials written

    // ---- merge 16 partials per token (threads 0..511), R12 threshold + flag
    if (tid < 512) {
        float best = NEGINF, second = NEGINF;
#pragma unroll
        for (int p = 0; p < 16; ++p) {
            float2 v = sPart[p * 512 + tid];
            float nb = fmaxf(best, v.x);
            second = fmaxf(fmaxf(second, v.y), fminf(best, v.x));
            best = nb;
        }
        unsigned ub = __float_as_uint(best);
        unsigned us = __float_as_uint(second);
        float bv = __uint_as_float(ub & 0xFFFFFC00u);
        float sv = __uint_as_float(us & 0xFFFFFC00u);
        int eb = (int)((ub >> 23) & 255u);
        int es = (int)((us >> 23) & 255u);
        int em = eb > es ? eb : es;
        em = em > 12 ? em : 12;
        // flag threshold = 4 * packing granule + eps (covers split-f16 error)
        float thr = __uint_as_float((unsigned)(em - 11) << 23) + DELTA_EPS;
        int k = 1023 - (int)(ub & 1023u);
        sOut[tid] = ((bv - sv) < thr) ? (k | FLAGBIT) : k;
    }
    __syncthreads();

    // ---- fused exact rescore (R12-proven): wave wid owns tokens [wid*32, wid*32+32)
    const int tokw = tok0 + wid * 32;
    int myval = 0;
    if (lane < 32) myval = sOut[wid * 32 + lane];
    unsigned long long mask = __ballot(lane < 32 && (myval & FLAGBIT));
    while (mask) {
        const int src = __ffsll(mask) - 1;
        mask &= mask - 1;
        const int token = tokw + src;   // wave-uniform

        float x[DIM];
#pragma unroll
        for (int j = 0; j < 8; ++j) {
            float4 aw = reinterpret_cast<const float4*>(w + (size_t)token * DIM)[j];
            float4 ac = reinterpret_cast<const float4*>(c + (size_t)token * DIM)[j];
            x[4 * j + 0] = aw.x - ac.x; x[4 * j + 1] = aw.y - ac.y;
            x[4 * j + 2] = aw.z - ac.z; x[4 * j + 3] = aw.w - ac.w;
        }
        float x2 = 0.f;
#pragma unroll
        for (int i = 0; i < DIM; ++i) x2 = fmaf(x[i], x[i], x2);

        float dmin = INFINITY;
        int   kbest = 0;
#pragma unroll 2
        for (int i = 0; i < 16; ++i) {
            const int k = lane + 64 * i;           // ascending per lane
            const float4* e4 = reinterpret_cast<const float4*>(cb) + (size_t)k * 8;
            float4 ev[8];
#pragma unroll
            for (int j = 0; j < 8; ++j) ev[j] = e4[j];
            float dot = 0.f;
#pragma unroll
            for (int j = 0; j < 8; ++j) {          // sequential order: j*4+0..3
                dot = fmaf(x[4 * j + 0], ev[j].x, dot);
                dot = fmaf(x[4 * j + 1], ev[j].y, dot);
                dot = fmaf(x[4 * j + 2], ev[j].z, dot);
                dot = fmaf(x[4 * j + 3], ev[j].w, dot);
            }
            float e2 = -2.0f * nhb[k];             // bit-exact |e|^2 (seq-fma in prep)
            float dd = fmaf(-2.0f, dot, x2) + e2;
            if (dd < dmin) { dmin = dd; kbest = k; }
        }
#pragma unroll
        for (int sh = 1; sh < 64; sh <<= 1) {
            float dB = __shfl_xor(dmin, sh);
            int   iB = __shfl_xor(kbest, sh);
            bool take = (dB < dmin) || (dB == dmin && iB < kbest);
            dmin = take ? dB : dmin;
            kbest = take ? iB : kbest;
        }
        if (lane == src) myval = kbest;   // exact index, flag cleared
    }
    if (lane < 32) out[tokw + lane] = myval;   // coalesced 128 B per wave
}

extern "C" void kernel_launch(void* const* d_in, const int* in_sizes, int n_in,
                              void* d_out, int out_size, void* d_ws, size_t ws_size,
                              hipStream_t stream) {
    const float* w  = (const float*)d_in[0];   // weights   [4194304]
    const float* c  = (const float*)d_in[1];   // condition [1,32,131072] flat
    const float* cb = (const float*)d_in[2];   // codebook  [1024,32]
    int* out = (int*)d_out;                    // int32 indices [131072]

    char* wsb = (char*)d_ws;
    float*    nhb = (float*)wsb;                       // 4 KB
    _Float16* Eh  = (_Float16*)(wsb + 4096);           // 64 KB (fragment-ordered)
    _Float16* El  = (_Float16*)(wsb + 4096 + 65536);   // 64 KB (fragment-ordered)

    vq_prep<<<NCODE / 64, 64, 0, stream>>>(cb, nhb, Eh, El);
    vq_main<<<NTOK / 512, 1024, 0, stream>>>(w, c, nhb, Eh, El, cb, out);
}

// Round 17
// 60.598 us; speedup vs baseline: 1.5394x; 1.5394x over previous
//
#include <hip/hip_runtime.h>

#define TOTAL     4194304
#define DIM       32
#define NTOK      (TOTAL / DIM)   // 131072 tokens
#define NCODE     1024
#define CCODES    256             // codes per chunk (4 chunks) -- proven R5/R12 staging
#define DELTA_EPS 2e-3f
#define FLAGBIT   0x40000000

typedef _Float16 half8   __attribute__((ext_vector_type(8)));
typedef float    floatx4 __attribute__((ext_vector_type(4)));

#define GLOAD_LDS16(g, l) \
    __builtin_amdgcn_global_load_lds((const __attribute__((address_space(1))) void*)(g), \
                                     (__attribute__((address_space(3))) void*)(l), 16, 0, 0)
#define GLOAD_LDS4(g, l) \
    __builtin_amdgcn_global_load_lds((const __attribute__((address_space(1))) void*)(g), \
                                     (__attribute__((address_space(3))) void*)(l), 4, 0, 0)

// ---------------- prep: codebook -> f16 hi/lo split in FRAGMENT ORDER + (-0.5*|e|^2) ----
// Fragment slot for code k (256-code chunks): chunk=k>>8, step=(k&255)>>4, l15=k&15;
// slot = chunk*1024 + step*64 + l4*16 + l15 (8 halves = 16 B per slot).
__global__ __launch_bounds__(64) void vq_prep(
    const float* __restrict__ cb, float* __restrict__ nhb,
    _Float16* __restrict__ Eh, _Float16* __restrict__ El)
{
    const int k = blockIdx.x * 64 + threadIdx.x;   // code id
    const float4* e4 = reinterpret_cast<const float4*>(cb) + (size_t)k * 8;
    float v[DIM];
    float4 t[8];
#pragma unroll
    for (int j = 0; j < 8; ++j) t[j] = e4[j];
#pragma unroll
    for (int j = 0; j < 8; ++j) {
        v[4 * j + 0] = t[j].x; v[4 * j + 1] = t[j].y;
        v[4 * j + 2] = t[j].z; v[4 * j + 3] = t[j].w;
    }
    float e2 = 0.0f;
#pragma unroll
    for (int i = 0; i < DIM; ++i) e2 = fmaf(v[i], v[i], e2);   // sequential: matches rescore
    nhb[k] = -0.5f * e2;

    const int chunk = k >> 8, within = k & 255;
    const int step = within >> 4, l15 = within & 15;
#pragma unroll
    for (int l4 = 0; l4 < 4; ++l4) {
        half8 h, lo;
#pragma unroll
        for (int j = 0; j < 8; ++j) {
            float x = v[l4 * 8 + j];
            _Float16 hh = (_Float16)x;
            h[j]  = hh;
            lo[j] = (_Float16)(x - (float)hh);
        }
        const int slot = chunk * 1024 + step * 64 + l4 * 16 + l15;
        *reinterpret_cast<half8*>(Eh + (size_t)slot * 8) = h;
        *reinterpret_cast<half8*>(El + (size_t)slot * 8) = lo;
    }
}

// ---------------- main: m=1 max-occupancy MFMA argmax + fused exact rescore ----------
// 1024 blocks x 512 thr (8 waves); wave owns 16 tokens (m=1) -> 8192 waves total =
// 32 waves/CU = 8/SIMD (VGPR pinned <=64 by launch_bounds). 4 chunks x 256 codes,
// LDS 33.5 KB -> 4 blocks/CU.
__global__ __launch_bounds__(512, 8) void vq_main(
    const float* __restrict__ w, const float* __restrict__ c,
    const float* __restrict__ nhb, const _Float16* __restrict__ Eh,
    const _Float16* __restrict__ El, const float* __restrict__ cb,
    int* __restrict__ out)
{
    __shared__ _Float16 sEh[1024 * 8];   // 16 KB: [step(16)][lane(64)][8 halves]
    __shared__ _Float16 sEl[1024 * 8];   // 16 KB
    __shared__ float    snh[CCODES];     // 1 KB
    __shared__ int      sOut[128];       // 512 B

    const int tid  = threadIdx.x;
    const int lane = tid & 63;
    const int wid  = tid >> 6;                      // 0..7
    const int tokw = blockIdx.x * 128 + wid * 16;   // 16 tokens per wave
    const int l15  = lane & 15;
    const int l4   = lane >> 4;

    // A fragment: 1 tile of 16 tokens. A[row=l15][k=l4*8+j]; exact x = xh + xl
    half8 xh, xl;
    {
        const int token = tokw + l15;
        const float4* pw = reinterpret_cast<const float4*>(w + (size_t)token * DIM + l4 * 8);
        const float4* pc = reinterpret_cast<const float4*>(c + (size_t)token * DIM + l4 * 8);
        float4 a0 = pw[0], a1 = pw[1], b0 = pc[0], b1 = pc[1];
        float xs[8] = {a0.x - b0.x, a0.y - b0.y, a0.z - b0.z, a0.w - b0.w,
                       a1.x - b1.x, a1.y - b1.y, a1.z - b1.z, a1.w - b1.w};
#pragma unroll
        for (int j = 0; j < 8; ++j) {
            _Float16 h = (_Float16)xs[j];
            xh[j] = h;
            xl[j] = (_Float16)(xs[j] - (float)h);
        }
    }

    const float NEGINF = __uint_as_float(0xFF800000u);
    float best[4], second[4];
#pragma unroll
    for (int q = 0; q < 4; ++q) { best[q] = NEGINF; second[q] = NEGINF; }

    for (int ch = 0; ch < 4; ++ch) {
        if (ch) __syncthreads();   // all waves done reading previous chunk before overwrite
        {   // stage 256 codes (hi+lo, 32 KB) + snh (1 KB), all-linear async global->LDS
            const _Float16* gh = Eh + (size_t)ch * 8192;
            const _Float16* gl = El + (size_t)ch * 8192;
#pragma unroll
            for (int r2 = 0; r2 < 2; ++r2) {
                const int slot = r2 * 512 + wid * 64;   // wave-uniform base
                GLOAD_LDS16(gh + (size_t)(slot + lane) * 8, sEh + (size_t)slot * 8);
                GLOAD_LDS16(gl + (size_t)(slot + lane) * 8, sEl + (size_t)slot * 8);
            }
            if (wid < 4) GLOAD_LDS4(nhb + ch * CCODES + wid * 64 + lane, snh + wid * 64);
        }
        __syncthreads();   // drain -> staged data visible

        // 16 steps of 16 codes, in pairs (med3 second-tracking)
#pragma unroll
        for (int sp = 0; sp < 8; ++sp) {
            const int sA = 2 * sp, sB = 2 * sp + 1;
            const half8 ehA = *reinterpret_cast<const half8*>(sEh + (size_t)(sA * 64 + lane) * 8);
            const half8 elA = *reinterpret_cast<const half8*>(sEl + (size_t)(sA * 64 + lane) * 8);
            const half8 ehB = *reinterpret_cast<const half8*>(sEh + (size_t)(sB * 64 + lane) * 8);
            const half8 elB = *reinterpret_cast<const half8*>(sEl + (size_t)(sB * 64 + lane) * 8);
            const float nhA = snh[sA * 16 + l15];
            const float nhB = snh[sB * 16 + l15];
            const unsigned ixA = 1023u - (unsigned)(ch * CCODES + sA * 16 + l15);
            const unsigned ixB = ixA - 16u;
            const floatx4 nA = {nhA, nhA, nhA, nhA};
            const floatx4 nB = {nhB, nhB, nhB, nhB};
            floatx4 aA = __builtin_amdgcn_mfma_f32_16x16x32_f16(xh, ehA, nA, 0, 0, 0);
            aA = __builtin_amdgcn_mfma_f32_16x16x32_f16(xl, ehA, aA, 0, 0, 0);
            aA = __builtin_amdgcn_mfma_f32_16x16x32_f16(xh, elA, aA, 0, 0, 0);
            floatx4 aB = __builtin_amdgcn_mfma_f32_16x16x32_f16(xh, ehB, nB, 0, 0, 0);
            aB = __builtin_amdgcn_mfma_f32_16x16x32_f16(xl, ehB, aB, 0, 0, 0);
            aB = __builtin_amdgcn_mfma_f32_16x16x32_f16(xh, elB, aB, 0, 0, 0);
#pragma unroll
            for (int r = 0; r < 4; ++r) {
                float pA = __uint_as_float((__float_as_uint(aA[r]) & 0xFFFFFC00u) | ixA);
                float pB = __uint_as_float((__float_as_uint(aB[r]) & 0xFFFFFC00u) | ixB);
                second[r] = fmaxf(second[r], __builtin_amdgcn_fmed3f(pA, pB, best[r]));
                best[r]   = fmaxf(fmaxf(best[r], pA), pB);
            }
        }
    }

    // reduce across the 16 code-lanes (xor over lane bits 0..3)
#pragma unroll
    for (int sh = 1; sh < 16; sh <<= 1) {
#pragma unroll
        for (int q = 0; q < 4; ++q) {
            float bB = __shfl_xor(best[q], sh);
            float sB = __shfl_xor(second[q], sh);
            second[q] = fmaxf(fmaxf(second[q], sB), fminf(best[q], bB));
            best[q]   = fmaxf(best[q], bB);
        }
    }

    // stage per-token results (k | optional FLAGBIT) -- R12's proven threshold
    if (l15 == 0) {
#pragma unroll
        for (int r = 0; r < 4; ++r) {
            unsigned ub = __float_as_uint(best[r]);
            unsigned us = __float_as_uint(second[r]);
            float bv = __uint_as_float(ub & 0xFFFFFC00u);
            float sv = __uint_as_float(us & 0xFFFFFC00u);
            int eb = (int)((ub >> 23) & 255u);
            int es = (int)((us >> 23) & 255u);
            int em = eb > es ? eb : es;
            em = em > 12 ? em : 12;
            // flag threshold = 4 * packing granule + eps (covers split-f16 error)
            float thr = __uint_as_float((unsigned)(em - 11) << 23) + DELTA_EPS;
            int k = 1023 - (int)(ub & 1023u);
            sOut[wid * 16 + l4 * 4 + r] = ((bv - sv) < thr) ? (k | FLAGBIT) : k;
        }
    }

    // lane i (<16) owns token tokw+i; rescore flagged tokens exactly (wave-cooperative).
    int myval = 0;
    if (lane < 16) myval = sOut[wid * 16 + lane];
    unsigned long long mask = __ballot(lane < 16 && (myval & FLAGBIT));
    while (mask) {
        const int src = __ffsll(mask) - 1;
        mask &= mask - 1;
        const int token = tokw + src;   // wave-uniform

        float x[DIM];
#pragma unroll
        for (int j = 0; j < 8; ++j) {
            float4 aw = reinterpret_cast<const float4*>(w + (size_t)token * DIM)[j];
            float4 ac = reinterpret_cast<const float4*>(c + (size_t)token * DIM)[j];
            x[4 * j + 0] = aw.x - ac.x; x[4 * j + 1] = aw.y - ac.y;
            x[4 * j + 2] = aw.z - ac.z; x[4 * j + 3] = aw.w - ac.w;
        }
        float x2 = 0.f;
#pragma unroll
        for (int i = 0; i < DIM; ++i) x2 = fmaf(x[i], x[i], x2);

        float dmin = INFINITY;
        int   kbest = 0;
#pragma unroll 2
        for (int i = 0; i < 16; ++i) {
            const int k = lane + 64 * i;           // ascending per lane
            const float4* e4 = reinterpret_cast<const float4*>(cb) + (size_t)k * 8;
            float4 ev[8];
#pragma unroll
            for (int j = 0; j < 8; ++j) ev[j] = e4[j];
            float dot = 0.f;
#pragma unroll
            for (int j = 0; j < 8; ++j) {          // sequential order: j*4+0..3
                dot = fmaf(x[4 * j + 0], ev[j].x, dot);
                dot = fmaf(x[4 * j + 1], ev[j].y, dot);
                dot = fmaf(x[4 * j + 2], ev[j].z, dot);
                dot = fmaf(x[4 * j + 3], ev[j].w, dot);
            }
            float e2 = -2.0f * nhb[k];             // bit-exact |e|^2 (seq-fma in prep)
            float dd = fmaf(-2.0f, dot, x2) + e2;
            if (dd < dmin) { dmin = dd; kbest = k; }
        }
#pragma unroll
        for (int sh = 1; sh < 64; sh <<= 1) {
            float dB = __shfl_xor(dmin, sh);
            int   iB = __shfl_xor(kbest, sh);
            bool take = (dB < dmin) || (dB == dmin && iB < kbest);
            dmin = take ? dB : dmin;
            kbest = take ? iB : kbest;
        }
        if (lane == src) myval = kbest;   // exact index, flag cleared
    }
    if (lane < 16) out[tokw + lane] = myval;   // coalesced 64 B per wave
}

extern "C" void kernel_launch(void* const* d_in, const int* in_sizes, int n_in,
                              void* d_out, int out_size, void* d_ws, size_t ws_size,
                              hipStream_t stream) {
    const float* w  = (const float*)d_in[0];   // weights   [4194304]
    const float* c  = (const float*)d_in[1];   // condition [1,32,131072] flat
    const float* cb = (const float*)d_in[2];   // codebook  [1024,32]
    int* out = (int*)d_out;                    // int32 indices [131072]

    char* wsb = (char*)d_ws;
    float*    nhb = (float*)wsb;                       // 4 KB
    _Float16* Eh  = (_Float16*)(wsb + 4096);           // 64 KB (fragment-ordered)
    _Float16* El  = (_Float16*)(wsb + 4096 + 65536);   // 64 KB (fragment-ordered)

    vq_prep<<<NCODE / 64, 64, 0, stream>>>(cb, nhb, Eh, El);
    vq_main<<<NTOK / 128, 512, 0, stream>>>(w, c, nhb, Eh, El, cb, out);
}

// Round 18
// 52.997 us; speedup vs baseline: 1.7602x; 1.1434x over previous
//
#include <hip/hip_runtime.h>

#define TOTAL     4194304
#define DIM       32
#define NTOK      (TOTAL / DIM)   // 131072 tokens
#define NCODE     1024
#define CCODES    256             // codes per chunk (4 chunks) -- proven R5 geometry
#define DELTA_EPS 2e-3f
#define FLAGBIT   0x40000000

typedef _Float16 half8   __attribute__((ext_vector_type(8)));
typedef float    floatx4 __attribute__((ext_vector_type(4)));

#define GLOAD_LDS16(g, l) \
    __builtin_amdgcn_global_load_lds((const __attribute__((address_space(1))) void*)(g), \
                                     (__attribute__((address_space(3))) void*)(l), 16, 0, 0)
#define GLOAD_LDS4(g, l) \
    __builtin_amdgcn_global_load_lds((const __attribute__((address_space(1))) void*)(g), \
                                     (__attribute__((address_space(3))) void*)(l), 4, 0, 0)

// ---------------- prep: codebook -> f16 hi/lo split in FRAGMENT ORDER + (-0.5*|e|^2) ----
// Fragment slot for code k (256-code chunks): chunk=k>>8, step=(k&255)>>4, l15=k&15;
// slot = chunk*1024 + step*64 + l4*16 + l15 (8 halves = 16 B per slot).
__global__ __launch_bounds__(64) void vq_prep(
    const float* __restrict__ cb, float* __restrict__ nhb,
    _Float16* __restrict__ Eh, _Float16* __restrict__ El)
{
    const int k = blockIdx.x * 64 + threadIdx.x;   // code id
    const float4* e4 = reinterpret_cast<const float4*>(cb) + (size_t)k * 8;
    float v[DIM];
    float4 t[8];
#pragma unroll
    for (int j = 0; j < 8; ++j) t[j] = e4[j];
#pragma unroll
    for (int j = 0; j < 8; ++j) {
        v[4 * j + 0] = t[j].x; v[4 * j + 1] = t[j].y;
        v[4 * j + 2] = t[j].z; v[4 * j + 3] = t[j].w;
    }
    float e2 = 0.0f;
#pragma unroll
    for (int i = 0; i < DIM; ++i) e2 = fmaf(v[i], v[i], e2);   // sequential: matches rescore
    nhb[k] = -0.5f * e2;

    const int chunk = k >> 8, within = k & 255;
    const int step = within >> 4, l15 = within & 15;
#pragma unroll
    for (int l4 = 0; l4 < 4; ++l4) {
        half8 h, lo;
#pragma unroll
        for (int j = 0; j < 8; ++j) {
            float x = v[l4 * 8 + j];
            _Float16 hh = (_Float16)x;
            h[j]  = hh;
            lo[j] = (_Float16)(x - (float)hh);
        }
        const int slot = chunk * 1024 + step * 64 + l4 * 16 + l15;
        *reinterpret_cast<half8*>(Eh + (size_t)slot * 8) = h;
        *reinterpret_cast<half8*>(El + (size_t)slot * 8) = lo;
    }
}

// ---------------- main: R5-proven MFMA argmax + LOW-VGPR fused exact rescore ----------
// 1024 blocks x 256 thr; wave owns 32 tokens (m=2); 4 chunks x 256 codes; LDS ~34.5 KB.
// The rescore tail stages the flagged token's x into per-wave LDS scratch and streams
// the codebook one float4 at a time -> tail register footprint ~12 regs, keeping the
// kernel at/below the 64-VGPR occupancy cliff.
__global__ __launch_bounds__(256) void vq_main(
    const float* __restrict__ w, const float* __restrict__ c,
    const float* __restrict__ nhb, const _Float16* __restrict__ Eh,
    const _Float16* __restrict__ El, const float* __restrict__ cb,
    int* __restrict__ out)
{
    __shared__ _Float16 sEh[1024 * 8];   // 16 KB: [step(16)][lane(64)][8 halves]
    __shared__ _Float16 sEl[1024 * 8];   // 16 KB
    __shared__ float    snh[CCODES];     // 1 KB
    __shared__ int      sOut[128];       // 512 B
    __shared__ float    sXf[4][DIM];     // 512 B per-wave rescore scratch

    const int tid  = threadIdx.x;
    const int lane = tid & 63;
    const int wid  = tid >> 6;
    const int tokw = blockIdx.x * 128 + wid * 32;   // 32 tokens per wave
    const int l15  = lane & 15;
    const int l4   = lane >> 4;

    // A fragments: 2 tiles of 16 tokens. A[row=l15][k=l4*8+j]; exact x = xh + xl
    half8 xh[2], xl[2];
#pragma unroll
    for (int m = 0; m < 2; ++m) {
        const int token = tokw + m * 16 + l15;
        const float4* pw = reinterpret_cast<const float4*>(w + (size_t)token * DIM + l4 * 8);
        const float4* pc = reinterpret_cast<const float4*>(c + (size_t)token * DIM + l4 * 8);
        float4 a0 = pw[0], a1 = pw[1], b0 = pc[0], b1 = pc[1];
        float xs[8] = {a0.x - b0.x, a0.y - b0.y, a0.z - b0.z, a0.w - b0.w,
                       a1.x - b1.x, a1.y - b1.y, a1.z - b1.z, a1.w - b1.w};
#pragma unroll
        for (int j = 0; j < 8; ++j) {
            _Float16 h = (_Float16)xs[j];
            xh[m][j] = h;
            xl[m][j] = (_Float16)(xs[j] - (float)h);
        }
    }

    const float NEGINF = __uint_as_float(0xFF800000u);
    float best[8], second[8];
#pragma unroll
    for (int q = 0; q < 8; ++q) { best[q] = NEGINF; second[q] = NEGINF; }

    for (int ch = 0; ch < 4; ++ch) {
        if (ch) __syncthreads();   // all waves done reading previous chunk before overwrite
        {   // stage 256 codes (hi+lo, 32 KB) + snh (1 KB), all-linear async global->LDS
            const _Float16* gh = Eh + (size_t)ch * 8192;
            const _Float16* gl = El + (size_t)ch * 8192;
#pragma unroll
            for (int r2 = 0; r2 < 4; ++r2) {
                const int slot = r2 * 256 + wid * 64;   // wave-uniform base
                GLOAD_LDS16(gh + (size_t)(slot + lane) * 8, sEh + (size_t)slot * 8);
                GLOAD_LDS16(gl + (size_t)(slot + lane) * 8, sEl + (size_t)slot * 8);
            }
            GLOAD_LDS4(nhb + ch * CCODES + wid * 64 + lane, snh + wid * 64);
        }
        __syncthreads();   // drain -> staged data visible

        // 16 steps of 16 codes, in pairs (med3 second-tracking) -- R5's proven loop
#pragma unroll
        for (int sp = 0; sp < 8; ++sp) {
            const int sA = 2 * sp, sB = 2 * sp + 1;
            const half8 ehA = *reinterpret_cast<const half8*>(sEh + (size_t)(sA * 64 + lane) * 8);
            const half8 elA = *reinterpret_cast<const half8*>(sEl + (size_t)(sA * 64 + lane) * 8);
            const half8 ehB = *reinterpret_cast<const half8*>(sEh + (size_t)(sB * 64 + lane) * 8);
            const half8 elB = *reinterpret_cast<const half8*>(sEl + (size_t)(sB * 64 + lane) * 8);
            const float nhA = snh[sA * 16 + l15];
            const float nhB = snh[sB * 16 + l15];
            const unsigned ixA = 1023u - (unsigned)(ch * CCODES + sA * 16 + l15);
            const unsigned ixB = ixA - 16u;
            const floatx4 nA = {nhA, nhA, nhA, nhA};
            const floatx4 nB = {nhB, nhB, nhB, nhB};
#pragma unroll
            for (int m = 0; m < 2; ++m) {
                floatx4 aA = __builtin_amdgcn_mfma_f32_16x16x32_f16(xh[m], ehA, nA, 0, 0, 0);
                aA = __builtin_amdgcn_mfma_f32_16x16x32_f16(xl[m], ehA, aA, 0, 0, 0);
                aA = __builtin_amdgcn_mfma_f32_16x16x32_f16(xh[m], elA, aA, 0, 0, 0);
                floatx4 aB = __builtin_amdgcn_mfma_f32_16x16x32_f16(xh[m], ehB, nB, 0, 0, 0);
                aB = __builtin_amdgcn_mfma_f32_16x16x32_f16(xl[m], ehB, aB, 0, 0, 0);
                aB = __builtin_amdgcn_mfma_f32_16x16x32_f16(xh[m], elB, aB, 0, 0, 0);
#pragma unroll
                for (int r = 0; r < 4; ++r) {
                    const int q = m * 4 + r;
                    float pA = __uint_as_float((__float_as_uint(aA[r]) & 0xFFFFFC00u) | ixA);
                    float pB = __uint_as_float((__float_as_uint(aB[r]) & 0xFFFFFC00u) | ixB);
                    second[q] = fmaxf(second[q], __builtin_amdgcn_fmed3f(pA, pB, best[q]));
                    best[q]   = fmaxf(fmaxf(best[q], pA), pB);
                }
            }
        }
    }

    // reduce across the 16 code-lanes (xor over lane bits 0..3)
#pragma unroll
    for (int sh = 1; sh < 16; sh <<= 1) {
#pragma unroll
        for (int q = 0; q < 8; ++q) {
            float bB = __shfl_xor(best[q], sh);
            float sB = __shfl_xor(second[q], sh);
            second[q] = fmaxf(fmaxf(second[q], sB), fminf(best[q], bB));
            best[q]   = fmaxf(best[q], bB);
        }
    }

    // stage per-token results (k | optional FLAGBIT) -- R12's proven threshold
    if (l15 == 0) {
#pragma unroll
        for (int m = 0; m < 2; ++m) {
#pragma unroll
            for (int r = 0; r < 4; ++r) {
                const int q = m * 4 + r;
                unsigned ub = __float_as_uint(best[q]);
                unsigned us = __float_as_uint(second[q]);
                float bv = __uint_as_float(ub & 0xFFFFFC00u);
                float sv = __uint_as_float(us & 0xFFFFFC00u);
                int eb = (int)((ub >> 23) & 255u);
                int es = (int)((us >> 23) & 255u);
                int em = eb > es ? eb : es;
                em = em > 12 ? em : 12;
                // flag threshold = 4 * packing granule + eps (covers split-f16 error)
                float thr = __uint_as_float((unsigned)(em - 11) << 23) + DELTA_EPS;
                int k = 1023 - (int)(ub & 1023u);
                sOut[wid * 32 + m * 16 + l4 * 4 + r] = ((bv - sv) < thr) ? (k | FLAGBIT) : k;
            }
        }
    }

    // lane i (<32) owns token tokw+i; rescore flagged tokens exactly (wave-cooperative).
    // LOW-VGPR path: x staged in per-wave LDS (in-order per wave, broadcast reads),
    // codebook streamed one float4 at a time. Same sequential-fma order -> bit-exact.
    int myval = 0;
    if (lane < 32) myval = sOut[wid * 32 + lane];
    unsigned long long mask = __ballot(lane < 32 && (myval & FLAGBIT));
    while (mask) {
        const int src = __ffsll(mask) - 1;
        mask &= mask - 1;
        const int token = tokw + src;   // wave-uniform

        if (lane < DIM)
            sXf[wid][lane] = w[(size_t)token * DIM + lane] - c[(size_t)token * DIM + lane];
        // LDS ops within a wave complete in order; compiler inserts lgkmcnt before reads.

        float x2 = 0.f;
#pragma unroll
        for (int i = 0; i < DIM; ++i) x2 = fmaf(sXf[wid][i], sXf[wid][i], x2);

        float dmin = INFINITY;
        int   kbest = 0;
        for (int i = 0; i < 16; ++i) {
            const int k = lane + 64 * i;           // ascending per lane
            const float4* e4 = reinterpret_cast<const float4*>(cb) + (size_t)k * 8;
            float dot = 0.f;
#pragma unroll
            for (int j = 0; j < 8; ++j) {          // sequential order: j*4+0..3
                float4 ev = e4[j];
                dot = fmaf(sXf[wid][4 * j + 0], ev.x, dot);
                dot = fmaf(sXf[wid][4 * j + 1], ev.y, dot);
                dot = fmaf(sXf[wid][4 * j + 2], ev.z, dot);
                dot = fmaf(sXf[wid][4 * j + 3], ev.w, dot);
            }
            float e2 = -2.0f * nhb[k];             // bit-exact |e|^2 (seq-fma in prep)
            float dd = fmaf(-2.0f, dot, x2) + e2;
            if (dd < dmin) { dmin = dd; kbest = k; }
        }
#pragma unroll
        for (int sh = 1; sh < 64; sh <<= 1) {
            float dB = __shfl_xor(dmin, sh);
            int   iB = __shfl_xor(kbest, sh);
            bool take = (dB < dmin) || (dB == dmin && iB < kbest);
            dmin = take ? dB : dmin;
            kbest = take ? iB : kbest;
        }
        if (lane == src) myval = kbest;   // exact index, flag cleared
    }
    if (lane < 32) out[tokw + lane] = myval;   // coalesced 128 B per wave
}

extern "C" void kernel_launch(void* const* d_in, const int* in_sizes, int n_in,
                              void* d_out, int out_size, void* d_ws, size_t ws_size,
                              hipStream_t stream) {
    const float* w  = (const float*)d_in[0];   // weights   [4194304]
    const float* c  = (const float*)d_in[1];   // condition [1,32,131072] flat
    const float* cb = (const float*)d_in[2];   // codebook  [1024,32]
    int* out = (int*)d_out;                    // int32 indices [131072]

    char* wsb = (char*)d_ws;
    float*    nhb = (float*)wsb;                       // 4 KB
    _Float16* Eh  = (_Float16*)(wsb + 4096);           // 64 KB (fragment-ordered)
    _Float16* El  = (_Float16*)(wsb + 4096 + 65536);   // 64 KB (fragment-ordered)

    vq_prep<<<NCODE / 64, 64, 0, stream>>>(cb, nhb, Eh, El);
    vq_main<<<NTOK / 128, 256, 0, stream>>>(w, c, nhb, Eh, El, cb, out);
}